// Round 5
// baseline (306.311 us; speedup 1.0000x reference)
//
#include <hip/hip_runtime.h>

#define B_    4
#define DEC_  256
#define ENC_  1024
#define D_    1024
#define A_    144
#define V_    50257
#define NROW_ (B_ * DEC_)
#define HS_   2048           // LDS hash slots (load factor 0.5)

typedef __attribute__((ext_vector_type(4))) float float4v;

// One block per (b,dec) row. Phases (block-local ordering via __syncthreads):
//  0: stage W_add, ids, hash init; p_gen reduction
//  1: scattered ovp prefetch into registers (addresses known up front)
//  2: base stream  out[row,:] = pg * ovp[row,:]
//  3: att dot -> val; LDS hash dedup + accumulate duplicate ids
//  4: leaders overwrite out[row,id] = pg*ovp_prefetched + sum ; write p_gen tail
__global__ __launch_bounds__(256) void k_fused(const int* __restrict__ ids,
                                               const float* __restrict__ att,
                                               const float* __restrict__ hid,
                                               const float* __restrict__ ovp,
                                               const float* __restrict__ Wp,
                                               const float* __restrict__ bp,
                                               const float* __restrict__ Wa,
                                               const float* __restrict__ ba,
                                               float* __restrict__ out,
                                               float* __restrict__ tail){
  __shared__ float red[4];
  __shared__ float sW[A_];
  __shared__ int   sid[ENC_];
  __shared__ int   hkey[HS_];
  __shared__ float hval[HS_];

  int row = blockIdx.x, t = threadIdx.x;
  int b = row >> 8;                       // row = b*DEC + dec

  // ---- phase 0 ----
  if (t < A_) sW[t] = Wa[t];
  for (int i = t; i < HS_; i += 256){ hkey[i] = -1; hval[i] = 0.f; }
  for (int i = t; i < ENC_; i += 256) sid[i] = ids[b * ENC_ + i];

  float4v hv = reinterpret_cast<const float4v*>(hid + (size_t)row * D_)[t];
  float4v wv = reinterpret_cast<const float4v*>(Wp)[t];
  float s = hv[0]*wv[0] + hv[1]*wv[1] + hv[2]*wv[2] + hv[3]*wv[3];
  for (int o = 32; o > 0; o >>= 1) s += __shfl_down(s, o, 64);
  if ((t & 63) == 0) red[t >> 6] = s;
  __syncthreads();
  float pg = 1.f / (1.f + __expf(-(red[0] + red[1] + red[2] + red[3] + bp[0])));

  // ---- phase 1: scattered prefetch (in flight during phase 2/3) ----
  size_t beg = (size_t)row * V_;
  int   myid[4];
  float pv[4];
#pragma unroll
  for (int k = 0; k < 4; ++k){
    myid[k] = sid[k * 256 + t];
    pv[k]   = ovp[beg + myid[k]];
  }

  // ---- phase 2: base stream for this row (16B-aligned body) ----
  {
    size_t end  = beg + V_;
    size_t beg4 = (beg + 3) & ~(size_t)3;
    size_t end4 = end & ~(size_t)3;
    int nhead = (int)(beg4 - beg);        // 0..3
    int ntail = (int)(end - end4);        // 0..3
    if (t < nhead) out[beg + t]  = pg * ovp[beg + t];
    if (t < ntail) out[end4 + t] = pg * ovp[end4 + t];
    const float4v* src = reinterpret_cast<const float4v*>(ovp + beg4);
    float4v*       dst = reinterpret_cast<float4v*>(out + beg4);
    unsigned n4 = (unsigned)((end4 - beg4) >> 2);    // ~12564
    for (unsigned i = t; i < n4; i += 256){
      float4v a = src[i];
      float4v o; o[0] = pg*a[0]; o[1] = pg*a[1]; o[2] = pg*a[2]; o[3] = pg*a[3];
      dst[i] = o;
    }
  }

  // ---- phase 3: att dot + hash dedup/accumulate ----
  float bav = ba[0];
  float one_m = 1.f - pg;
  unsigned slotk[4];
  int      leadk[4];
#pragma unroll
  for (int k = 0; k < 4; ++k){
    int e = k * 256 + t;
    const float4v* ap = reinterpret_cast<const float4v*>(att + ((size_t)row * ENC_ + e) * A_);
    float acc = 0.f;
#pragma unroll
    for (int j = 0; j < A_ / 4; ++j){
      float4v v = ap[j];
      acc += v[0]*sW[j*4+0] + v[1]*sW[j*4+1] + v[2]*sW[j*4+2] + v[3]*sW[j*4+3];
    }
    float x = acc + bav;
    x = x > 0.f ? x : 0.f;
    float val = one_m * x;

    int id = myid[k];
    unsigned h = (((unsigned)id * 2654435761u) >> 16) & (HS_ - 1);
    int lead = 0;
    while (true){
      int prev = atomicCAS(&hkey[h], -1, id);
      if (prev == -1){ lead = 1; break; }
      if (prev == id) break;
      h = (h + 1) & (HS_ - 1);
    }
    atomicAdd(&hval[h], val);
    slotk[k] = h;
    leadk[k] = lead;
  }
  __syncthreads();   // hval complete; also orders phase-2 writes before phase-4 overwrites

  // ---- phase 4: leader writes (no global reads) ----
#pragma unroll
  for (int k = 0; k < 4; ++k){
    if (leadk[k]) out[beg + myid[k]] = pg * pv[k] + hval[slotk[k]];
  }
  if (t == 0) tail[row] = pg;
}

extern "C" void kernel_launch(void* const* d_in, const int* in_sizes, int n_in,
                              void* d_out, int out_size, void* d_ws, size_t ws_size,
                              hipStream_t stream) {
  (void)in_sizes; (void)n_in; (void)d_ws; (void)ws_size; (void)out_size;
  const int*   ids = (const int*)  d_in[0];
  const float* att = (const float*)d_in[1];
  const float* hid = (const float*)d_in[2];
  const float* ovp = (const float*)d_in[3];
  const float* Wp  = (const float*)d_in[4];
  const float* bp  = (const float*)d_in[5];
  const float* Wa  = (const float*)d_in[6];
  const float* ba  = (const float*)d_in[7];
  float* out  = (float*)d_out;
  float* tail = out + (size_t)NROW_ * V_;   // p_gen output (fp32)

  k_fused<<<NROW_, 256, 0, stream>>>(ids, att, hid, ovp, Wp, bp, Wa, ba, out, tail);
}

// Round 6
// 272.541 us; speedup vs baseline: 1.1239x; 1.1239x over previous
//
#include <hip/hip_runtime.h>

#define B_    4
#define DEC_  256
#define ENC_  1024
#define D_    1024
#define A_    144
#define V_    50257
#define NROW_ (B_ * DEC_)

typedef __attribute__((ext_vector_type(4))) float float4v;

// ---------------- kernel 1: p_gen = sigmoid(hidden . W_pgen + b) -> out tail (fp32) ----------------
__global__ void k_pgen(const float* __restrict__ hid, const float* __restrict__ Wp,
                       const float* __restrict__ bp, float* __restrict__ tail){
  int row = blockIdx.x, t = threadIdx.x;
  float4v hv = reinterpret_cast<const float4v*>(hid + (size_t)row * D_)[t];
  float4v wv = reinterpret_cast<const float4v*>(Wp)[t];
  float s = hv[0]*wv[0] + hv[1]*wv[1] + hv[2]*wv[2] + hv[3]*wv[3];
  for (int o = 32; o > 0; o >>= 1) s += __shfl_down(s, o, 64);
  __shared__ float red[4];
  if ((t & 63) == 0) red[t >> 6] = s;
  __syncthreads();
  if (t == 0){
    float tot = red[0] + red[1] + red[2] + red[3] + bp[0];
    tail[row] = 1.f / (1.f + __expf(-tot));
  }
}

// ---------------- kernel 2: out = p_gen * ovp (fp32, 4-wide, grid-stride) ----------------
__global__ void k_base(const float* __restrict__ ovp, const float* __restrict__ tail,
                       float* __restrict__ out){
  const unsigned N4 = (unsigned)(((size_t)NROW_ * V_) / 4);   // 51,463,168 / 4 exact
  unsigned stride = gridDim.x * blockDim.x;
  for (unsigned vi = blockIdx.x * blockDim.x + threadIdx.x; vi < N4; vi += stride){
    unsigned i0 = vi * 4u;
    unsigned r0 = i0 / (unsigned)V_;
    unsigned r1 = (i0 + 3u) / (unsigned)V_;
    float4v a = reinterpret_cast<const float4v*>(ovp)[vi];
    float4v o;
    float pg0 = tail[r0];
    if (r0 == r1){
#pragma unroll
      for (int k = 0; k < 4; ++k) o[k] = pg0 * a[k];
    } else {
      float pg1 = tail[r1];
      unsigned bnd = r1 * (unsigned)V_;
#pragma unroll
      for (int k = 0; k < 4; ++k)
        o[k] = (((i0 + (unsigned)k) < bnd) ? pg0 : pg1) * a[k];
    }
    reinterpret_cast<float4v*>(out)[vi] = o;
  }
}

// ---------------- kernel 3: scatter-add via HW atomics ----------------
// one thread per (row,e): val = (1-pg)*relu(att[row,e,:].W_add + ba);
// out[row*V + ids[b,e]] += val  (global fp32 atomic; dedup in hardware)
__global__ __launch_bounds__(256) void k_scat(const int* __restrict__ ids,
                                              const float* __restrict__ att,
                                              const float* __restrict__ Wa,
                                              const float* __restrict__ ba,
                                              const float* __restrict__ tail,
                                              float* __restrict__ out){
  __shared__ float sW[A_];
  int t = threadIdx.x;
  if (t < A_) sW[t] = Wa[t];
  __syncthreads();

  unsigned tid = blockIdx.x * 256u + t;       // 0 .. 1,048,575
  unsigned row = tid >> 10;                   // / ENC_
  unsigned e   = tid & (ENC_ - 1);
  unsigned b   = row >> 8;                    // / DEC_

  float pg  = tail[row];
  int   id  = ids[b * ENC_ + e];              // coalesced within wave
  float bav = ba[0];

  const float4v* ap = reinterpret_cast<const float4v*>(att + (size_t)tid * A_);
  float a0 = 0.f, a1 = 0.f, a2 = 0.f, a3 = 0.f;
#pragma unroll
  for (int j = 0; j < 9; ++j){                // 9 * 4 float4 = 144 floats
    float4v v0 = ap[4*j+0], v1 = ap[4*j+1], v2 = ap[4*j+2], v3 = ap[4*j+3];
    const float* w = &sW[16*j];
    a0 += v0[0]*w[0]  + v0[1]*w[1]  + v0[2]*w[2]  + v0[3]*w[3];
    a1 += v1[0]*w[4]  + v1[1]*w[5]  + v1[2]*w[6]  + v1[3]*w[7];
    a2 += v2[0]*w[8]  + v2[1]*w[9]  + v2[2]*w[10] + v2[3]*w[11];
    a3 += v3[0]*w[12] + v3[1]*w[13] + v3[2]*w[14] + v3[3]*w[15];
  }
  float x = (a0 + a1) + (a2 + a3) + bav;
  x = x > 0.f ? x : 0.f;
  float val = (1.f - pg) * x;

  unsafeAtomicAdd(out + (size_t)row * V_ + id, val);   // global_atomic_add_f32
}

extern "C" void kernel_launch(void* const* d_in, const int* in_sizes, int n_in,
                              void* d_out, int out_size, void* d_ws, size_t ws_size,
                              hipStream_t stream) {
  (void)in_sizes; (void)n_in; (void)d_ws; (void)ws_size; (void)out_size;
  const int*   ids = (const int*)  d_in[0];
  const float* att = (const float*)d_in[1];
  const float* hid = (const float*)d_in[2];
  const float* ovp = (const float*)d_in[3];
  const float* Wp  = (const float*)d_in[4];
  const float* bp  = (const float*)d_in[5];
  const float* Wa  = (const float*)d_in[6];
  const float* ba  = (const float*)d_in[7];
  float* out  = (float*)d_out;
  float* tail = out + (size_t)NROW_ * V_;   // p_gen output (fp32)

  k_pgen<<<NROW_, 256, 0, stream>>>(hid, Wp, bp, tail);
  k_base<<<4096,  256, 0, stream>>>(ovp, tail, out);
  k_scat<<<(NROW_ * ENC_) / 256, 256, 0, stream>>>(ids, att, Wa, ba, tail, out);
}

// Round 7
// 250.044 us; speedup vs baseline: 1.2250x; 1.0900x over previous
//
#include <hip/hip_runtime.h>

#define B_    4
#define DEC_  256
#define ENC_  1024
#define D_    1024
#define A_    144
#define V_    50257
#define NROW_ (B_ * DEC_)

typedef __attribute__((ext_vector_type(4))) float float4v;

// ---------------- kernel 1: p_gen = sigmoid(hidden . W_pgen + b) -> out tail (fp32) ----------------
__global__ void k_pgen(const float* __restrict__ hid, const float* __restrict__ Wp,
                       const float* __restrict__ bp, float* __restrict__ tail){
  int row = blockIdx.x, t = threadIdx.x;
  float4v hv = reinterpret_cast<const float4v*>(hid + (size_t)row * D_)[t];
  float4v wv = reinterpret_cast<const float4v*>(Wp)[t];
  float s = hv[0]*wv[0] + hv[1]*wv[1] + hv[2]*wv[2] + hv[3]*wv[3];
  for (int o = 32; o > 0; o >>= 1) s += __shfl_down(s, o, 64);
  __shared__ float red[4];
  if ((t & 63) == 0) red[t >> 6] = s;
  __syncthreads();
  if (t == 0){
    float tot = red[0] + red[1] + red[2] + red[3] + bp[0];
    tail[row] = 1.f / (1.f + __expf(-tot));
  }
}

// ---------------- kernel 2: out = p_gen * ovp (fp32, 4-wide, grid-stride) ----------------
__global__ void k_base(const float* __restrict__ ovp, const float* __restrict__ tail,
                       float* __restrict__ out){
  const unsigned N4 = (unsigned)(((size_t)NROW_ * V_) / 4);   // 51,463,168 / 4 exact
  unsigned stride = gridDim.x * blockDim.x;
  for (unsigned vi = blockIdx.x * blockDim.x + threadIdx.x; vi < N4; vi += stride){
    unsigned i0 = vi * 4u;
    unsigned r0 = i0 / (unsigned)V_;
    unsigned r1 = (i0 + 3u) / (unsigned)V_;
    float4v a = reinterpret_cast<const float4v*>(ovp)[vi];
    float4v o;
    float pg0 = tail[r0];
    if (r0 == r1){
#pragma unroll
      for (int k = 0; k < 4; ++k) o[k] = pg0 * a[k];
    } else {
      float pg1 = tail[r1];
      unsigned bnd = r1 * (unsigned)V_;
#pragma unroll
      for (int k = 0; k < 4; ++k)
        o[k] = (((i0 + (unsigned)k) < bnd) ? pg0 : pg1) * a[k];
    }
    reinterpret_cast<float4v*>(out)[vi] = o;
  }
}

// ---------------- kernel 3: scatter-add, 4 lanes per (row,e) position ----------------
// lane group t&3 reads float4s {k, k+4, ..., k+32} of its position: each wave load
// instruction consumes 16 FULL 64B lines (no L1-reuse dependence). Partial dots
// combine via 2 shfl_xor; leader lane issues the fp32 HW atomic.
__global__ __launch_bounds__(256) void k_scat(const int* __restrict__ ids,
                                              const float* __restrict__ att,
                                              const float* __restrict__ Wa,
                                              const float* __restrict__ ba,
                                              const float* __restrict__ tail,
                                              float* __restrict__ out){
  __shared__ float sW[A_];
  int t = threadIdx.x;
  if (t < A_) sW[t] = Wa[t];
  __syncthreads();

  unsigned gtid  = blockIdx.x * 256u + t;
  unsigned pos   = gtid >> 2;                 // 0 .. 1,048,575  (row,e)
  unsigned lane4 = t & 3u;
  unsigned row   = pos >> 10;                 // / ENC_
  unsigned e     = pos & (ENC_ - 1);
  unsigned b     = row >> 8;                  // / DEC_

  const float4v* ap = reinterpret_cast<const float4v*>(att + (size_t)pos * A_);
  float acc0 = 0.f, acc1 = 0.f;
#pragma unroll
  for (int j = 0; j < 9; ++j){                // float4 index lane4 + 4j
    float4v v = ap[lane4 + 4u*j];
    const float* w = &sW[4u*(lane4 + 4u*j)];
    float p = v[0]*w[0] + v[1]*w[1] + v[2]*w[2] + v[3]*w[3];
    if (j & 1) acc1 += p; else acc0 += p;
  }
  float acc = acc0 + acc1;
  acc += __shfl_xor(acc, 1, 64);
  acc += __shfl_xor(acc, 2, 64);

  if (lane4 == 0){
    float pg = tail[row];
    float x = acc + ba[0];
    x = x > 0.f ? x : 0.f;
    float val = (1.f - pg) * x;
    int id = ids[b * ENC_ + e];
    unsafeAtomicAdd(out + (size_t)row * V_ + id, val);   // global_atomic_add_f32
  }
}

extern "C" void kernel_launch(void* const* d_in, const int* in_sizes, int n_in,
                              void* d_out, int out_size, void* d_ws, size_t ws_size,
                              hipStream_t stream) {
  (void)in_sizes; (void)n_in; (void)d_ws; (void)ws_size; (void)out_size;
  const int*   ids = (const int*)  d_in[0];
  const float* att = (const float*)d_in[1];
  const float* hid = (const float*)d_in[2];
  const float* ovp = (const float*)d_in[3];
  const float* Wp  = (const float*)d_in[4];
  const float* bp  = (const float*)d_in[5];
  const float* Wa  = (const float*)d_in[6];
  const float* ba  = (const float*)d_in[7];
  float* out  = (float*)d_out;
  float* tail = out + (size_t)NROW_ * V_;   // p_gen output (fp32)

  k_pgen<<<NROW_, 256, 0, stream>>>(hid, Wp, bp, tail);
  k_base<<<4096,  256, 0, stream>>>(ovp, tail, out);
  k_scat<<<(NROW_ * ENC_ * 4) / 256, 256, 0, stream>>>(ids, att, Wa, ba, tail, out);
}